// Round 1
// baseline (231.039 us; speedup 1.0000x reference)
//
#include <hip/hip_runtime.h>
#include <math.h>

#define NBOX 2048
#define NBATCH 8
#define MAX_INST 100
#define MIN_CONF 0.15f
#define NMS_THR 0.3f
#define BLOCK 256

// Decode one box exactly in the reference's f32 op order (no FMA contraction).
__device__ inline float4 decode_box(float4 r, float4 d,
                                    float wy1, float wx1, float wy2, float wx2) {
    float h  = __fsub_rn(r.z, r.x);
    float w  = __fsub_rn(r.w, r.y);
    float dy = __fmul_rn(d.x, 0.1f);
    float dx = __fmul_rn(d.y, 0.1f);
    float dh = __fmul_rn(d.z, 0.2f);
    float dw = __fmul_rn(d.w, 0.2f);
    float cy = __fadd_rn(__fadd_rn(r.x, __fmul_rn(0.5f, h)), __fmul_rn(dy, h));
    float cx = __fadd_rn(__fadd_rn(r.y, __fmul_rn(0.5f, w)), __fmul_rn(dx, w));
    float h2 = __fmul_rn(h, expf(dh));
    float w2 = __fmul_rn(w, expf(dw));
    float y1 = __fsub_rn(cy, __fmul_rn(0.5f, h2));
    float x1 = __fsub_rn(cx, __fmul_rn(0.5f, w2));
    float y2 = __fadd_rn(y1, h2);
    float x2 = __fadd_rn(x1, w2);
    float4 b;
    b.x = fminf(fmaxf(y1, wy1), wy2);
    b.y = fminf(fmaxf(x1, wx1), wx2);
    b.z = fminf(fmaxf(y2, wy1), wy2);
    b.w = fminf(fmaxf(x2, wx1), wx2);
    return b;
}

__global__ __launch_bounds__(BLOCK)
void detect_refine_kernel(const float* __restrict__ rois,
                          const float* __restrict__ scores_in,
                          const float* __restrict__ deltas,
                          const float* __restrict__ window,
                          float* __restrict__ out) {
    const int b   = blockIdx.x;
    const int tid = threadIdx.x;

    __shared__ unsigned long long keys[NBOX];   // 16 KiB: (~score_bits)<<32 | idx
    __shared__ float4 sboxes[NBOX];             // 32 KiB: sorted decoded boxes
    __shared__ float  sscores[NBOX];            //  8 KiB
    __shared__ unsigned char removed[NBOX];     //  2 KiB (1 = suppressed/invalid)
    __shared__ int    s_pick;
    __shared__ float4 s_curbox;

    const float wy1 = window[b * 4 + 0];
    const float wx1 = window[b * 4 + 1];
    const float wy2 = window[b * 4 + 2];
    const float wx2 = window[b * 4 + 3];

    float* outb = out + (size_t)b * MAX_INST * 5;
    // Zero this batch's output (harness poisons d_out between replays).
    for (int i = tid; i < MAX_INST * 5; i += BLOCK) outb[i] = 0.0f;

    // Phase A: build sort keys. Descending score, ascending original index
    // (matches stable jnp.argsort(-scores)).
    for (int i = tid; i < NBOX; i += BLOCK) {
        float s = scores_in[b * NBOX + i];
        unsigned u = __float_as_uint(s);
        u = (u & 0x80000000u) ? ~u : (u | 0x80000000u);   // order-preserving map
        keys[i] = ((unsigned long long)(~u) << 32) | (unsigned)i;
    }

    // Phase B: bitonic sort ascending (= score descending).
    for (int k = 2; k <= NBOX; k <<= 1) {
        for (int j = k >> 1; j > 0; j >>= 1) {
            __syncthreads();
            for (int t = tid; t < NBOX / 2; t += BLOCK) {
                int i = 2 * t - (t & (j - 1));
                int p = i | j;
                bool up = ((i & k) == 0);
                unsigned long long a = keys[i], c = keys[p];
                bool sw = up ? (a > c) : (a < c);
                if (sw) { keys[i] = c; keys[p] = a; }
            }
        }
    }
    __syncthreads();

    // Gather: recompute box/score for each sorted slot.
    for (int i = tid; i < NBOX; i += BLOCK) {
        int oi = (int)(keys[i] & 0xFFFFFFFFull);
        float4 r = ((const float4*)rois)[b * NBOX + oi];
        float4 d = ((const float4*)deltas)[b * NBOX + oi];
        float  s = scores_in[b * NBOX + oi];
        sboxes[i]  = decode_box(r, d, wy1, wx1, wy2, wx2);
        sscores[i] = s;
        removed[i] = (s >= MIN_CONF) ? 0 : 1;   // invalid == pre-removed
    }
    __syncthreads();

    // Phase C: greedy NMS, early-exit after MAX_INST keeps.
    int cursor = 0, count = 0;                  // only thread 0's copies matter
    while (true) {
        if (tid == 0) {
            int pick = -1;
            while (cursor < NBOX) {
                if (!removed[cursor]) { pick = cursor; break; }
                ++cursor;
            }
            if (pick >= 0) {
                float4 bb = sboxes[pick];
                float* o = outb + count * 5;
                o[0] = bb.x; o[1] = bb.y; o[2] = bb.z; o[3] = bb.w;
                o[4] = sscores[pick];
                ++count;
                ++cursor;
                s_curbox = bb;
                s_pick = (count >= MAX_INST) ? -1 : pick;  // last keep: no suppress needed
            } else {
                s_pick = -1;
            }
        }
        __syncthreads();
        int pick = s_pick;
        if (pick < 0) break;
        float4 bb = s_curbox;
        float areaA = __fmul_rn(__fsub_rn(bb.z, bb.x), __fsub_rn(bb.w, bb.y));
        for (int j = pick + 1 + tid; j < NBOX; j += BLOCK) {
            if (removed[j]) continue;
            float4 cb = sboxes[j];
            float iy1 = fmaxf(bb.x, cb.x);
            float ix1 = fmaxf(bb.y, cb.y);
            float iy2 = fminf(bb.z, cb.z);
            float ix2 = fminf(bb.w, cb.w);
            float ih = fmaxf(__fsub_rn(iy2, iy1), 0.0f);
            float iw = fmaxf(__fsub_rn(ix2, ix1), 0.0f);
            float inter = __fmul_rn(ih, iw);
            float areaB = __fmul_rn(__fsub_rn(cb.z, cb.x), __fsub_rn(cb.w, cb.y));
            float uni = __fadd_rn(__fsub_rn(__fadd_rn(areaA, areaB), inter), 1e-8f);
            float iou = __fdiv_rn(inter, uni);
            if (iou > NMS_THR) removed[j] = 1;
        }
        __syncthreads();
    }
}

extern "C" void kernel_launch(void* const* d_in, const int* in_sizes, int n_in,
                              void* d_out, int out_size, void* d_ws, size_t ws_size,
                              hipStream_t stream) {
    const float* rois    = (const float*)d_in[0];
    const float* scores  = (const float*)d_in[1];
    const float* deltas  = (const float*)d_in[2];
    const float* window  = (const float*)d_in[3];
    float* out = (float*)d_out;
    detect_refine_kernel<<<NBATCH, BLOCK, 0, stream>>>(rois, scores, deltas, window, out);
}

// Round 2
// 94.099 us; speedup vs baseline: 2.4553x; 2.4553x over previous
//
#include <hip/hip_runtime.h>
#include <math.h>

#define NBOX 2048
#define NBATCH 8
#define MAX_INST 100
#define MIN_CONF 0.15f
#define NMS_THR 0.3f
#define BLOCK 512
#define NWAVE (BLOCK / 64)

// Decode one box exactly in the reference's f32 op order (no FMA contraction).
__device__ inline float4 decode_box(float4 r, float4 d,
                                    float wy1, float wx1, float wy2, float wx2) {
    float h  = __fsub_rn(r.z, r.x);
    float w  = __fsub_rn(r.w, r.y);
    float dy = __fmul_rn(d.x, 0.1f);
    float dx = __fmul_rn(d.y, 0.1f);
    float dh = __fmul_rn(d.z, 0.2f);
    float dw = __fmul_rn(d.w, 0.2f);
    float cy = __fadd_rn(__fadd_rn(r.x, __fmul_rn(0.5f, h)), __fmul_rn(dy, h));
    float cx = __fadd_rn(__fadd_rn(r.y, __fmul_rn(0.5f, w)), __fmul_rn(dx, w));
    float h2 = __fmul_rn(h, expf(dh));
    float w2 = __fmul_rn(w, expf(dw));
    float y1 = __fsub_rn(cy, __fmul_rn(0.5f, h2));
    float x1 = __fsub_rn(cx, __fmul_rn(0.5f, w2));
    float y2 = __fadd_rn(y1, h2);
    float x2 = __fadd_rn(x1, w2);
    float4 b;
    b.x = fminf(fmaxf(y1, wy1), wy2);
    b.y = fminf(fmaxf(x1, wx1), wx2);
    b.z = fminf(fmaxf(y2, wy1), wy2);
    b.w = fminf(fmaxf(x2, wx1), wx2);
    return b;
}

// IoU with 'a' as the earlier (kept / row) box — exact reference op order.
__device__ inline float iou_pair(float4 a, float4 b) {
    float areaA = __fmul_rn(__fsub_rn(a.z, a.x), __fsub_rn(a.w, a.y));
    float areaB = __fmul_rn(__fsub_rn(b.z, b.x), __fsub_rn(b.w, b.y));
    float iy1 = fmaxf(a.x, b.x);
    float ix1 = fmaxf(a.y, b.y);
    float iy2 = fminf(a.z, b.z);
    float ix2 = fminf(a.w, b.w);
    float ih = fmaxf(__fsub_rn(iy2, iy1), 0.0f);
    float iw = fmaxf(__fsub_rn(ix2, ix1), 0.0f);
    float inter = __fmul_rn(ih, iw);
    float uni = __fadd_rn(__fsub_rn(__fadd_rn(areaA, areaB), inter), 1e-8f);
    return __fdiv_rn(inter, uni);
}

__global__ __launch_bounds__(BLOCK)
void detect_refine_kernel(const float* __restrict__ rois,
                          const float* __restrict__ scores_in,
                          const float* __restrict__ deltas,
                          const float* __restrict__ window,
                          float* __restrict__ out) {
    const int b    = blockIdx.x;
    const int tid  = threadIdx.x;
    const int lane = tid & 63;
    const int wid  = tid >> 6;

    __shared__ unsigned long long keys[NBOX];   // 16 KiB
    __shared__ float4 sboxes[NBOX];             // 32 KiB
    __shared__ float  sscores[NBOX];            //  8 KiB
    __shared__ unsigned char removed[NBOX];     //  2 KiB
    __shared__ unsigned long long masks[64];    // 512 B: window IoU>thr rows
    __shared__ int s_keptslot[MAX_INST];        // kept slots of current window
    __shared__ int s_m;

    const float wy1 = window[b * 4 + 0];
    const float wx1 = window[b * 4 + 1];
    const float wy2 = window[b * 4 + 2];
    const float wx2 = window[b * 4 + 3];

    float* outb = out + (size_t)b * MAX_INST * 5;
    for (int i = tid; i < MAX_INST * 5; i += BLOCK) outb[i] = 0.0f;

    // Phase A: sort keys (descending score, ascending original index).
    for (int i = tid; i < NBOX; i += BLOCK) {
        float s = scores_in[b * NBOX + i];
        unsigned u = __float_as_uint(s);
        u = (u & 0x80000000u) ? ~u : (u | 0x80000000u);
        keys[i] = ((unsigned long long)(~u) << 32) | (unsigned)i;
    }

    // Phase B: bitonic sort ascending (= score descending).
    for (int k = 2; k <= NBOX; k <<= 1) {
        for (int j = k >> 1; j > 0; j >>= 1) {
            __syncthreads();
            for (int t = tid; t < NBOX / 2; t += BLOCK) {
                int i = 2 * t - (t & (j - 1));
                int p = i | j;
                bool up = ((i & k) == 0);
                unsigned long long a = keys[i], c = keys[p];
                bool sw = up ? (a > c) : (a < c);
                if (sw) { keys[i] = c; keys[p] = a; }
            }
        }
    }
    __syncthreads();

    // Gather: decode box/score for each sorted slot.
    for (int i = tid; i < NBOX; i += BLOCK) {
        int oi = (int)(keys[i] & 0xFFFFFFFFull);
        float4 r = ((const float4*)rois)[b * NBOX + oi];
        float4 d = ((const float4*)deltas)[b * NBOX + oi];
        float  s = scores_in[b * NBOX + oi];
        sboxes[i]  = decode_box(r, d, wy1, wx1, wy2, wx2);
        sscores[i] = s;
        removed[i] = (s >= MIN_CONF) ? 0 : 1;
    }
    __syncthreads();

    // Phase C: window-batched greedy NMS (64 candidates per round).
    int count = 0;
    unsigned long long aliveReg = 0;   // live only on wave 0
    for (int cursor = 0; cursor < NBOX && count < MAX_INST; cursor += 64) {
        // Build 64x64 IoU>thr bitmask rows (8 rows per wave) + alive ballot.
        float4 bj = sboxes[cursor + lane];
        for (int i = wid; i < 64; i += NWAVE) {
            float4 bi = sboxes[cursor + i];
            bool pred = (lane > i) && (iou_pair(bi, bj) > NMS_THR);
            unsigned long long bal = __ballot(pred);
            if (lane == 0) masks[i] = bal;
        }
        if (wid == 0) {
            aliveReg = __ballot(removed[cursor + lane] == 0);
        }
        __syncthreads();

        // Wave 0: resolve the window's greedy chain in registers.
        if (wid == 0) {
            unsigned long long mymask = masks[lane];
            unsigned long long alive  = aliveReg;
            int m = 0;
            const int maxm = MAX_INST - count;
            while (alive && m < maxm) {
                int i = __builtin_ctzll(alive);
                if (lane == 0) s_keptslot[m] = cursor + i;
                ++m;
                unsigned long long mi = __shfl(mymask, i);
                alive = alive & ~mi & ~(1ull << i);
            }
            if (lane == 0) s_m = m;
        }
        __syncthreads();

        const int m = s_m;
        // Write output rows for this window's keeps (in order).
        if (tid < m * 5) {
            int r = tid / 5, c = tid % 5;
            int s = s_keptslot[r];
            float4 bb = sboxes[s];
            float v;
            if      (c == 0) v = bb.x;
            else if (c == 1) v = bb.y;
            else if (c == 2) v = bb.z;
            else if (c == 3) v = bb.w;
            else             v = sscores[s];
            outb[(count + r) * 5 + c] = v;
        }
        count += m;
        if (count >= MAX_INST) break;   // done — tail suppression irrelevant

        // Batched tail suppression: every later box vs ALL kept of this window.
        if (m > 0) {
            for (int j = cursor + 64 + tid; j < NBOX; j += BLOCK) {
                if (removed[j]) continue;
                float4 cb = sboxes[j];
                bool sup = false;
                for (int k = 0; k < m; ++k) {
                    float4 kb = sboxes[s_keptslot[k]];
                    sup |= (iou_pair(kb, cb) > NMS_THR);
                }
                if (sup) removed[j] = 1;
            }
        }
        __syncthreads();
    }
}

extern "C" void kernel_launch(void* const* d_in, const int* in_sizes, int n_in,
                              void* d_out, int out_size, void* d_ws, size_t ws_size,
                              hipStream_t stream) {
    const float* rois    = (const float*)d_in[0];
    const float* scores  = (const float*)d_in[1];
    const float* deltas  = (const float*)d_in[2];
    const float* window  = (const float*)d_in[3];
    float* out = (float*)d_out;
    detect_refine_kernel<<<NBATCH, BLOCK, 0, stream>>>(rois, scores, deltas, window, out);
}

// Round 3
// 48.903 us; speedup vs baseline: 4.7244x; 1.9242x over previous
//
#include <hip/hip_runtime.h>
#include <math.h>

#define NBOX 2048
#define NBATCH 8
#define MAX_INST 100
#define MIN_CONF 0.15f
#define NMS_THR 0.3f
#define BLOCK 512
#define NWAVE (BLOCK / 64)

typedef unsigned long long ull;

// Decode one box exactly in the reference's f32 op order (no FMA contraction).
__device__ inline float4 decode_box(float4 r, float4 d,
                                    float wy1, float wx1, float wy2, float wx2) {
    float h  = __fsub_rn(r.z, r.x);
    float w  = __fsub_rn(r.w, r.y);
    float dy = __fmul_rn(d.x, 0.1f);
    float dx = __fmul_rn(d.y, 0.1f);
    float dh = __fmul_rn(d.z, 0.2f);
    float dw = __fmul_rn(d.w, 0.2f);
    float cy = __fadd_rn(__fadd_rn(r.x, __fmul_rn(0.5f, h)), __fmul_rn(dy, h));
    float cx = __fadd_rn(__fadd_rn(r.y, __fmul_rn(0.5f, w)), __fmul_rn(dx, w));
    float h2 = __fmul_rn(h, expf(dh));
    float w2 = __fmul_rn(w, expf(dw));
    float y1 = __fsub_rn(cy, __fmul_rn(0.5f, h2));
    float x1 = __fsub_rn(cx, __fmul_rn(0.5f, w2));
    float y2 = __fadd_rn(y1, h2);
    float x2 = __fadd_rn(x1, w2);
    float4 b;
    b.x = fminf(fmaxf(y1, wy1), wy2);
    b.y = fminf(fmaxf(x1, wx1), wx2);
    b.z = fminf(fmaxf(y2, wy1), wy2);
    b.w = fminf(fmaxf(x2, wx1), wx2);
    return b;
}

// Exact reference op order (IoU is symmetric in its two boxes).
__device__ inline float iou_pair(float4 a, float4 b) {
    float areaA = __fmul_rn(__fsub_rn(a.z, a.x), __fsub_rn(a.w, a.y));
    float areaB = __fmul_rn(__fsub_rn(b.z, b.x), __fsub_rn(b.w, b.y));
    float iy1 = fmaxf(a.x, b.x);
    float ix1 = fmaxf(a.y, b.y);
    float iy2 = fminf(a.z, b.z);
    float ix2 = fminf(a.w, b.w);
    float ih = fmaxf(__fsub_rn(iy2, iy1), 0.0f);
    float iw = fmaxf(__fsub_rn(ix2, ix1), 0.0f);
    float inter = __fmul_rn(ih, iw);
    float uni = __fadd_rn(__fsub_rn(__fadd_rn(areaA, areaB), inter), 1e-8f);
    return __fdiv_rn(inter, uni);
}

__device__ inline ull shfl_xor64(ull x, int d) {
    unsigned lo = (unsigned)x, hi = (unsigned)(x >> 32);
    lo = __shfl_xor(lo, d);
    hi = __shfl_xor(hi, d);
    return ((ull)hi << 32) | lo;
}

__device__ inline ull shfl64(ull x, int src) {
    unsigned lo = (unsigned)x, hi = (unsigned)(x >> 32);
    lo = __shfl(lo, src);
    hi = __shfl(hi, src);
    return ((ull)hi << 32) | lo;
}

__device__ inline void cmpsel(ull& a, ull& b, bool takeMinA) {
    ull mn = a < b ? a : b;
    ull mx = a < b ? b : a;
    a = takeMinA ? mn : mx;
    b = takeMinA ? mx : mn;
}

__global__ __launch_bounds__(BLOCK)
void detect_refine_kernel(const float* __restrict__ rois,
                          const float* __restrict__ scores_in,
                          const float* __restrict__ deltas,
                          const float* __restrict__ window,
                          float* __restrict__ out) {
    const int b    = blockIdx.x;
    const int tid  = threadIdx.x;
    const int lane = tid & 63;
    const int wid  = tid >> 6;

    __shared__ ull    keys[NBOX];        // 16 KiB  (~score_bits)<<32 | orig_idx
    __shared__ float4 sboxes[NBOX];      // 32 KiB  decoded boxes, by ORIGINAL idx
    __shared__ float  sscores[NBOX];     //  8 KiB  by ORIGINAL idx
    __shared__ ull    masks[64];         // in-window IoU>thr rows
    __shared__ ull    dead8[NWAVE];      // per-wave "dead vs prev-kept" ballots
    __shared__ float4 s_keptbox[MAX_INST];
    __shared__ int    s_keptslot[64];
    __shared__ int    s_m;
    __shared__ ull    s_alive;

    const float wy1 = window[b * 4 + 0];
    const float wx1 = window[b * 4 + 1];
    const float wy2 = window[b * 4 + 2];
    const float wx2 = window[b * 4 + 3];

    float* outb = out + (size_t)b * MAX_INST * 5;
    for (int i = tid; i < MAX_INST * 5; i += BLOCK) outb[i] = 0.0f;

    // ---- Phase A1: coalesced load + decode, stored by ORIGINAL index ----
    for (int e = tid; e < NBOX; e += BLOCK) {
        float4 r = ((const float4*)rois)[b * NBOX + e];
        float4 d = ((const float4*)deltas)[b * NBOX + e];
        float  s = scores_in[b * NBOX + e];
        sboxes[e]  = decode_box(r, d, wy1, wx1, wy2, wx2);
        sscores[e] = s;
    }

    // ---- Phase A2: sort keys in registers (4 consecutive elements/thread) ----
    const int e0 = tid * 4;
    ull v[4];
    {
        float4 sc = ((const float4*)(scores_in + (size_t)b * NBOX))[tid];
        float s4[4] = {sc.x, sc.y, sc.z, sc.w};
#pragma unroll
        for (int s = 0; s < 4; ++s) {
            unsigned u = __float_as_uint(s4[s]);
            u = (u & 0x80000000u) ? ~u : (u | 0x80000000u);
            v[s] = ((ull)(~u) << 32) | (unsigned)(e0 + s);
        }
    }

    // ---- Phase B: bitonic sort ascending (= score descending, stable) ----
    // j>=256: LDS exchange; j in [4,128]: shfl_xor(j/4); j in {2,1}: registers.
    for (unsigned k = 2; k <= NBOX; k <<= 1) {
        if (k >= 512) {
#pragma unroll
            for (int s = 0; s < 4; ++s) keys[e0 + s] = v[s];
            __syncthreads();
            for (unsigned j = k >> 1; j >= 256; j >>= 1) {
                for (int t = tid; t < NBOX / 2; t += BLOCK) {
                    int i = 2 * t - (t & (j - 1));
                    int p = i | j;
                    bool up = ((i & k) == 0);
                    ull a = keys[i], c = keys[p];
                    bool sw = up ? (a > c) : (a < c);
                    if (sw) { keys[i] = c; keys[p] = a; }
                }
                __syncthreads();
            }
#pragma unroll
            for (int s = 0; s < 4; ++s) v[s] = keys[e0 + s];
        }
        unsigned jstart = ((k >> 1) > 128u) ? 128u : (k >> 1);
        for (unsigned j = jstart; j >= 4; j >>= 1) {
            int d = (int)(j >> 2);
#pragma unroll
            for (int s = 0; s < 4; ++s) {
                ull p = shfl_xor64(v[s], d);
                int e = e0 + s;
                bool takeMin = (((e & j) == 0) == ((e & k) == 0));
                v[s] = takeMin ? (v[s] < p ? v[s] : p) : (v[s] > p ? v[s] : p);
            }
        }
        if (k >= 4) {   // j == 2
            bool up = ((e0 & k) == 0);
            cmpsel(v[0], v[2], up);
            cmpsel(v[1], v[3], up);
        }
        {               // j == 1
            bool upA = ((e0 & k) == 0);
            bool upB = (((e0 + 2) & k) == 0);
            cmpsel(v[0], v[1], upA);
            cmpsel(v[2], v[3], upB);
        }
    }
#pragma unroll
    for (int s = 0; s < 4; ++s) keys[e0 + s] = v[s];
    __syncthreads();

    // ---- Phase C: window-batched greedy NMS, suppression deferred to keeps ----
    int count = 0;
    for (int cursor = 0; cursor < NBOX && count < MAX_INST; cursor += 64) {
        // Candidate for this lane.
        int   oi_j = (int)(keys[cursor + lane] & 0xFFFFFFFFull);
        float4 bj  = sboxes[oi_j];
        float  sj  = sscores[oi_j];

        // Task 1: dead vs previously-kept boxes (strided over waves, OR later).
        bool deadp = (sj < MIN_CONF);
        for (int kk = wid; kk < count; kk += NWAVE)
            deadp |= (iou_pair(s_keptbox[kk], bj) > NMS_THR);
        ull bal = __ballot(deadp);
        if (lane == 0) dead8[wid] = bal;

        // Task 2: in-window pairwise mask rows (8 rows per wave).
        for (int i = wid; i < 64; i += NWAVE) {
            int   oi_i = (int)(keys[cursor + i] & 0xFFFFFFFFull);
            float4 bi  = sboxes[oi_i];
            bool pred  = (lane > i) && (iou_pair(bi, bj) > NMS_THR);
            ull  m     = __ballot(pred);
            if (lane == 0) masks[i] = m;
        }
        __syncthreads();

        // Wave 0: resolve the window's greedy chain in registers.
        if (wid == 0) {
            ull dead = dead8[0];
#pragma unroll
            for (int w = 1; w < NWAVE; ++w) dead |= dead8[w];
            ull alive = ~dead;
            ull mymask = masks[lane];
            int m = 0;
            const int maxm = MAX_INST - count;
            while (alive && m < maxm) {
                int i = __builtin_ctzll(alive);
                if (lane == 0) s_keptslot[m] = cursor + i;
                ++m;
                ull mi = shfl64(mymask, i);
                alive = alive & ~mi & ~(1ull << i);
            }
            if (lane == 0) s_m = m;
        }
        __syncthreads();

        const int m = s_m;
        if (tid < m) {
            int slot = s_keptslot[tid];
            int oi   = (int)(keys[slot] & 0xFFFFFFFFull);
            float4 bb = sboxes[oi];
            s_keptbox[count + tid] = bb;
            float* o = outb + (size_t)(count + tid) * 5;
            o[0] = bb.x; o[1] = bb.y; o[2] = bb.z; o[3] = bb.w;
            o[4] = sscores[oi];
        }
        count += m;
        __syncthreads();
    }
}

extern "C" void kernel_launch(void* const* d_in, const int* in_sizes, int n_in,
                              void* d_out, int out_size, void* d_ws, size_t ws_size,
                              hipStream_t stream) {
    const float* rois    = (const float*)d_in[0];
    const float* scores  = (const float*)d_in[1];
    const float* deltas  = (const float*)d_in[2];
    const float* window  = (const float*)d_in[3];
    float* out = (float*)d_out;
    detect_refine_kernel<<<NBATCH, BLOCK, 0, stream>>>(rois, scores, deltas, window, out);
}